// Round 8
// baseline (211.162 us; speedup 1.0000x reference)
//
#include <hip/hip_runtime.h>
#include <math.h>

// Problem: B=16, LQ=1024, LK=1024, DK=256, DV=256, fp32 in/out, mask int32.
// Identity: softmax_k(q_s + k_s with mask) == mask-weighted softmax of k_s alone
// (q_s cancels; masked entries are exactly -1e9 -> weight 0). query never read.
// k_s ~ N(0,256) => softmax mass concentrates in top ~30-60 keys; chunk-0
// (top-64) provably terminates ~all rows (e_64 ~ e^-26 * Z << 1e-5 * Z).
//
// R1: bitonic sort -> counting-sort select_kernel.
// R2 (FAILED, 218us): serial dependent scalar loads -> L2 latency chain.
// R3-R7 (50-62us): three different per-row walk structures all latency-bound
//   (~17k cy/wave critical path, VALU <20%, ~1 TB/s effective).
// R8: amortize per-batch work across rows. One wave = 4 rows of one batch:
//   - top-64 (e,k) metadata lane-parallel, shared by the 4 rows;
//   - 4 independent mask gathers -> 4 ballot u64s in SGPRs;
//   - walk = COMPILE-TIME 64-iteration loop (compiler can pipeline; the
//     runtime-NA loops of R6/R7 could not), PIPE=8 rotating load buffers;
//     each uniform V load feeds 4 rows; weights are scalar-selected
//     (s_cselect) and enter v_fmac as the single SGPR operand;
//   - Z per row via one ballot-masked butterfly before the walk.
//   Loads/row 32->16, mask 64MB streamed -> ~43MB gathered, walk VALU ~2.5k
//   cy/wave. Floor ~8us (L2 256MB + gather 43MB + VALU overlapped).

#define NB     16
#define NL     1024     // LQ == LK
#define ND     256      // DK == DV
#define NBKT   128      // buckets of width 1.0 in log-space

// ---------------- Kernel A: ks[b,k] = dot(key[b,k,:], w) -----------------
__global__ __launch_bounds__(256)
void ks_kernel(const float* __restrict__ key, const float* __restrict__ w,
               float* __restrict__ ks) {
    int wid  = threadIdx.x >> 6;
    int lane = threadIdx.x & 63;
    int row  = blockIdx.x * 4 + wid;               // 0 .. NB*NL-1
    const float4* krow = (const float4*)(key + (size_t)row * ND);
    float4 kv = krow[lane];
    float4 wv = ((const float4*)w)[lane];
    float p = kv.x * wv.x + kv.y * wv.y + kv.z * wv.z + kv.w * wv.w;
    #pragma unroll
    for (int off = 32; off > 0; off >>= 1)
        p += __shfl_xor(p, off, 64);
    if (lane == 0) ks[row] = p;
}

// ------- Kernel B: per batch: max, e=exp(ks-m), counting sort by -------
// ------- bucket floor(m-v), exact suffix mass at chunk boundaries -------
// 256 threads (4 waves), 4 entries/thread. Order within a bucket arbitrary;
// attn breaks on the EXACT suffix mass rem[] of the actual gathered order.
__global__ __launch_bounds__(256)
void select_kernel(const float* __restrict__ ks,
                   float2* __restrict__ pk, float* __restrict__ rem) {
    __shared__ float se[NL];       // gathered e values (bucket order)
    __shared__ int   cnt[NBKT];    // histogram
    __shared__ int   cur[NBKT];    // scan -> scatter cursors
    __shared__ float wred[4];      // per-wave max
    __shared__ float csum[16];     // per-chunk sums
    const int b    = blockIdx.x;
    const int t    = threadIdx.x;
    const int lane = t & 63;
    const int wid  = t >> 6;
    const float* ksb = ks + b * NL;

    if (t < NBKT) cnt[t] = 0;

    // 4 entries per thread, coalesced (stride 256)
    float v0 = ksb[t], v1 = ksb[t + 256], v2 = ksb[t + 512], v3 = ksb[t + 768];

    // block max: thread max4 -> wave shuffle reduce -> 4-way LDS combine
    float mx = fmaxf(fmaxf(v0, v1), fmaxf(v2, v3));
    #pragma unroll
    for (int off = 32; off > 0; off >>= 1)
        mx = fmaxf(mx, __shfl_xor(mx, off, 64));
    if (lane == 0) wred[wid] = mx;
    __syncthreads();                                        // #1 (also covers cnt=0)
    const float m = fmaxf(fmaxf(wred[0], wred[1]), fmaxf(wred[2], wred[3]));

    float e0 = __expf(v0 - m), e1 = __expf(v1 - m);
    float e2 = __expf(v2 - m), e3 = __expf(v3 - m);
    int b0 = (int)fminf(m - v0, (float)(NBKT - 1));
    int b1 = (int)fminf(m - v1, (float)(NBKT - 1));
    int b2 = (int)fminf(m - v2, (float)(NBKT - 1));
    int b3 = (int)fminf(m - v3, (float)(NBKT - 1));
    atomicAdd(&cnt[b0], 1); atomicAdd(&cnt[b1], 1);
    atomicAdd(&cnt[b2], 1); atomicAdd(&cnt[b3], 1);
    __syncthreads();                                        // #2

    // exclusive scan of cnt[128] by wave 0 via shuffles (no barriers inside)
    if (wid == 0) {
        int a  = cnt[lane];
        int b2v = cnt[lane + 64];
        int sa = a, sb = b2v;
        #pragma unroll
        for (int d = 1; d < 64; d <<= 1) {
            int na = __shfl_up(sa, d, 64);
            int nb = __shfl_up(sb, d, 64);
            if (lane >= d) { sa += na; sb += nb; }
        }
        int tot = __shfl(sa, 63, 64);
        sb += tot;
        cur[lane]      = sa - a;
        cur[lane + 64] = sb - b2v;
    }
    __syncthreads();                                        // #3

    // scatter (bijective: every entry gets a unique p in [0, NL))
    int p0 = atomicAdd(&cur[b0], 1);
    int p1 = atomicAdd(&cur[b1], 1);
    int p2 = atomicAdd(&cur[b2], 1);
    int p3 = atomicAdd(&cur[b3], 1);
    se[p0] = e0; pk[b * NL + p0] = make_float2(e0, __int_as_float(t));
    se[p1] = e1; pk[b * NL + p1] = make_float2(e1, __int_as_float(t + 256));
    se[p2] = e2; pk[b * NL + p2] = make_float2(e2, __int_as_float(t + 512));
    se[p3] = e3; pk[b * NL + p3] = make_float2(e3, __int_as_float(t + 768));
    __syncthreads();                                        // #4

    // per-chunk sums: wave w reduces chunks 4w..4w+3
    #pragma unroll
    for (int cc = 0; cc < 4; ++cc) {
        int chunk = wid * 4 + cc;
        float s = se[chunk * 64 + lane];
        #pragma unroll
        for (int off = 32; off > 0; off >>= 1)
            s += __shfl_xor(s, off, 64);
        if (lane == 0) csum[chunk] = s;
    }
    __syncthreads();                                        // #5

    // suffix masses at the 16 boundary slots attn actually reads
    if (t == 0) {
        float run = 0.0f;
        for (int c = 15; c >= 0; --c) {
            rem[b * NL + c * 64 + 63] = run;
            run += csum[c];
        }
    }
}

// ---------------- Kernel C: out[b,q,:] = sum_k p * value[b,k,:] ----------
// 256 threads = 4 waves; ONE WAVE = 4 CONSECUTIVE ROWS of one batch.
// Per wave: lane-parallel (e,k) for top-64 (shared by the 4 rows); 4
// independent mask gathers -> ballots (SGPR u64s); Z per row via masked
// butterfly; then a fully-unrolled 64-entry walk with PIPE rotating buffers:
// each uniform V load (L2-hot) feeds all 4 rows, weights scalar-selected.
__global__ __launch_bounds__(256)
void attn_kernel(const float* __restrict__ value, const int* __restrict__ mask,
                 const float2* __restrict__ pk, const float* __restrict__ rem,
                 float* __restrict__ out) {
    const int wid  = threadIdx.x >> 6;
    const int lane = threadIdx.x & 63;
    const int row0 = blockIdx.x * 16 + wid * 4;   // 4 rows: row0..row0+3
    const int b    = row0 >> 10;
    const int base = b << 10;

    const float4* vbase = (const float4*)(value + ((size_t)b << 10) * ND);
    const float2* pk_g  = pk + base;

    // top-64 metadata, lane-parallel (shared by all rows of the batch)
    float2 p0 = pk_g[lane];
    float e0  = p0.x;
    int   k0  = __float_as_int(p0.y);
    int   e0i = __float_as_int(e0);

    // 4 independent mask gathers, issued together
    int mv0 = mask[(size_t)(row0 + 0) * NL + k0];
    int mv1 = mask[(size_t)(row0 + 1) * NL + k0];
    int mv2 = mask[(size_t)(row0 + 2) * NL + k0];
    int mv3 = mask[(size_t)(row0 + 3) * NL + k0];
    unsigned long long bm0 = __ballot(mv0 != 0);
    unsigned long long bm1 = __ballot(mv1 != 0);
    unsigned long long bm2 = __ballot(mv2 != 0);
    unsigned long long bm3 = __ballot(mv3 != 0);

    // Z per row: butterfly of mask-selected e (uniform result)
    auto zsum = [&](unsigned long long bm) -> float {
        float wz = ((bm >> lane) & 1ull) ? e0 : 0.0f;
        #pragma unroll
        for (int off = 32; off > 0; off >>= 1)
            wz += __shfl_xor(wz, off, 64);
        return wz;
    };
    float z0 = zsum(bm0), z1 = zsum(bm1), z2 = zsum(bm2), z3 = zsum(bm3);

    // ---- walk: compile-time 64 iterations, PIPE-deep rotating buffers ----
    float4 acc0 = make_float4(0.f, 0.f, 0.f, 0.f);
    float4 acc1 = make_float4(0.f, 0.f, 0.f, 0.f);
    float4 acc2 = make_float4(0.f, 0.f, 0.f, 0.f);
    float4 acc3 = make_float4(0.f, 0.f, 0.f, 0.f);

    constexpr int PIPE = 8;
    float4 vb[PIPE];
    #pragma unroll
    for (int i = 0; i < PIPE; ++i) {
        int ki = __builtin_amdgcn_readlane(k0, i);       // uniform -> SGPR base
        vb[i] = vbase[(size_t)ki * 64 + lane];
    }
    #pragma unroll
    for (int i = 0; i < 64; ++i) {
        float4 v = vb[i & (PIPE - 1)];
        if (i + PIPE < 64) {                             // compile-time branch
            int kn = __builtin_amdgcn_readlane(k0, i + PIPE);
            vb[i & (PIPE - 1)] = vbase[(size_t)kn * 64 + lane];
        }
        float ei = __int_as_float(__builtin_amdgcn_readlane(e0i, i));
        float w0 = ((bm0 >> i) & 1ull) ? ei : 0.0f;      // scalar selects
        float w1 = ((bm1 >> i) & 1ull) ? ei : 0.0f;
        float w2 = ((bm2 >> i) & 1ull) ? ei : 0.0f;
        float w3 = ((bm3 >> i) & 1ull) ? ei : 0.0f;
        acc0.x += w0 * v.x; acc0.y += w0 * v.y; acc0.z += w0 * v.z; acc0.w += w0 * v.w;
        acc1.x += w1 * v.x; acc1.y += w1 * v.y; acc1.z += w1 * v.z; acc1.w += w1 * v.w;
        acc2.x += w2 * v.x; acc2.y += w2 * v.y; acc2.z += w2 * v.z; acc2.w += w2 * v.w;
        acc3.x += w3 * v.x; acc3.y += w3 * v.y; acc3.z += w3 * v.z; acc3.w += w3 * v.w;
    }

    // ---- per-row epilogue: done check, rare deep chunks, store ----
    const float remv = rem[base + 63];

    auto finish_row = [&](int r, float4 acc, float Z) {
        const int* mrow = mask + (size_t)(row0 + r) * NL;
        bool done = (remv <= 1e-5f * Z);     // Z==0 -> rem>0 -> continue
        for (int c = 1; c < 16 && !done; ++c) {           // ~never taken
            float2 p = pk_g[c * 64 + lane];
            float e  = p.x;
            int   k  = __float_as_int(p.y);
            bool mb  = (mrow[k] != 0);
            float dz = mb ? e : 0.0f;
            #pragma unroll
            for (int off = 32; off > 0; off >>= 1)
                dz += __shfl_xor(dz, off, 64);
            unsigned long long bmx = __ballot(mb);
            int eI = __float_as_int(e);
            for (int i = 0; i < 64; ++i) {                // rolled: rare path
                float ei = __int_as_float(__builtin_amdgcn_readlane(eI, i));
                int   ki = __builtin_amdgcn_readlane(k, i);
                float w  = ((bmx >> i) & 1ull) ? ei : 0.0f;
                float4 v = vbase[(size_t)ki * 64 + lane];
                acc.x += w * v.x; acc.y += w * v.y;
                acc.z += w * v.z; acc.w += w * v.w;
            }
            Z += dz;
            done = (rem[base + c * 64 + 63] <= 1e-5f * Z);
        }
        float4* orow = (float4*)(out + (size_t)(row0 + r) * ND);
        if (Z > 0.0f) {
            float inv = 1.0f / Z;
            orow[lane] = make_float4(acc.x * inv, acc.y * inv,
                                     acc.z * inv, acc.w * inv);
        } else {
            // all-masked row: softmax over constant -1e9 -> uniform average
            float4 s = make_float4(0.f, 0.f, 0.f, 0.f);
            for (int k = 0; k < NL; ++k) {
                float4 v = vbase[(size_t)k * 64 + lane];
                s.x += v.x; s.y += v.y; s.z += v.z; s.w += v.w;
            }
            const float inv = 1.0f / (float)NL;
            orow[lane] = make_float4(s.x * inv, s.y * inv, s.z * inv, s.w * inv);
        }
    };
    finish_row(0, acc0, z0);
    finish_row(1, acc1, z1);
    finish_row(2, acc2, z2);
    finish_row(3, acc3, z3);
}

extern "C" void kernel_launch(void* const* d_in, const int* in_sizes, int n_in,
                              void* d_out, int out_size, void* d_ws, size_t ws_size,
                              hipStream_t stream) {
    // setup_inputs order: query, key, value, w, mask   (query unused!)
    const float* key   = (const float*)d_in[1];
    const float* value = (const float*)d_in[2];
    const float* w     = (const float*)d_in[3];
    const int*   mask  = (const int*)d_in[4];
    float*       outp  = (float*)d_out;

    float*  ks  = (float*)d_ws;                  // 16*1024 f32
    float2* pkb = (float2*)(ks + NB * NL);       // 16*1024 f32x2 (e, idx) bucket-desc
    float*  rem = (float*)(pkb + NB * NL);       // 16*1024 f32 suffix masses

    ks_kernel    <<<NB * NL / 4, 256, 0, stream>>>(key, w, ks);
    select_kernel<<<NB, 256, 0, stream>>>(ks, pkb, rem);
    attn_kernel  <<<NB * NL / 16, 256, 0, stream>>>(value, mask, pkb, rem, outp);
}

// Round 9
// 159.837 us; speedup vs baseline: 1.3211x; 1.3211x over previous
//
#include <hip/hip_runtime.h>
#include <math.h>

// Problem: B=16, LQ=1024, LK=1024, DK=256, DV=256, fp32 in/out, mask int32.
// Identity: softmax_k(q_s + k_s with mask) == mask-weighted softmax of k_s alone
// (q_s cancels; masked entries are exactly -1e9 -> weight 0). query never read.
// k_s ~ N(0,256) => softmax mass concentrates in top ~30-60 keys; chunk-0
// (top-64) provably terminates ~all rows (e_64 ~ e^-26 * Z << 1e-5 * Z).
//
// R1: bitonic sort -> counting-sort select_kernel.
// R2 (FAILED 218us): serial dependent scalar loads -> L2 latency chain.
// R3-R7 (50-62us): per-row walks all latency-bound. Best = R4 (50us):
//   LDS-staged top-64 V rows, per-row LDS walk.
// R8 (FAILED 95us): 4-rows/wave + global V walk + PIPE=8 prefetch buffers ->
//   VGPR 156, occupancy 5.9%: register pipeline killed residency.
// R9 = R4 x R8 hybrid, avoiding both failure modes: LDS-staged V (no prefetch
//   registers) + 4 rows/wave (each ds_read feeds 4 accumulators; weights are
//   SGPR s_cselects from 4 ballot masks; no compaction/bpermute). 512 blocks
//   x 8 waves x 64KB LDS -> 2 blocks/CU, stage/walk overlap across blocks.
//   Mask gathers issued at kernel top; latency hides under stage+barrier.

#define NB     16
#define NL     1024     // LQ == LK
#define ND     256      // DK == DV
#define NBKT   128      // buckets of width 1.0 in log-space

// ---------------- Kernel A: ks[b,k] = dot(key[b,k,:], w) -----------------
__global__ __launch_bounds__(256)
void ks_kernel(const float* __restrict__ key, const float* __restrict__ w,
               float* __restrict__ ks) {
    int wid  = threadIdx.x >> 6;
    int lane = threadIdx.x & 63;
    int row  = blockIdx.x * 4 + wid;               // 0 .. NB*NL-1
    const float4* krow = (const float4*)(key + (size_t)row * ND);
    float4 kv = krow[lane];
    float4 wv = ((const float4*)w)[lane];
    float p = kv.x * wv.x + kv.y * wv.y + kv.z * wv.z + kv.w * wv.w;
    #pragma unroll
    for (int off = 32; off > 0; off >>= 1)
        p += __shfl_xor(p, off, 64);
    if (lane == 0) ks[row] = p;
}

// ------- Kernel B: per batch: max, e=exp(ks-m), counting sort by -------
// ------- bucket floor(m-v), exact suffix mass at chunk boundaries -------
// 256 threads (4 waves), 4 entries/thread. Order within a bucket arbitrary;
// attn breaks on the EXACT suffix mass rem[] of the actual gathered order.
__global__ __launch_bounds__(256)
void select_kernel(const float* __restrict__ ks,
                   float2* __restrict__ pk, float* __restrict__ rem) {
    __shared__ float se[NL];       // gathered e values (bucket order)
    __shared__ int   cnt[NBKT];    // histogram
    __shared__ int   cur[NBKT];    // scan -> scatter cursors
    __shared__ float wred[4];      // per-wave max
    __shared__ float csum[16];     // per-chunk sums
    const int b    = blockIdx.x;
    const int t    = threadIdx.x;
    const int lane = t & 63;
    const int wid  = t >> 6;
    const float* ksb = ks + b * NL;

    if (t < NBKT) cnt[t] = 0;

    // 4 entries per thread, coalesced (stride 256)
    float v0 = ksb[t], v1 = ksb[t + 256], v2 = ksb[t + 512], v3 = ksb[t + 768];

    // block max: thread max4 -> wave shuffle reduce -> 4-way LDS combine
    float mx = fmaxf(fmaxf(v0, v1), fmaxf(v2, v3));
    #pragma unroll
    for (int off = 32; off > 0; off >>= 1)
        mx = fmaxf(mx, __shfl_xor(mx, off, 64));
    if (lane == 0) wred[wid] = mx;
    __syncthreads();                                        // #1 (also covers cnt=0)
    const float m = fmaxf(fmaxf(wred[0], wred[1]), fmaxf(wred[2], wred[3]));

    float e0 = __expf(v0 - m), e1 = __expf(v1 - m);
    float e2 = __expf(v2 - m), e3 = __expf(v3 - m);
    int b0 = (int)fminf(m - v0, (float)(NBKT - 1));
    int b1 = (int)fminf(m - v1, (float)(NBKT - 1));
    int b2 = (int)fminf(m - v2, (float)(NBKT - 1));
    int b3 = (int)fminf(m - v3, (float)(NBKT - 1));
    atomicAdd(&cnt[b0], 1); atomicAdd(&cnt[b1], 1);
    atomicAdd(&cnt[b2], 1); atomicAdd(&cnt[b3], 1);
    __syncthreads();                                        // #2

    // exclusive scan of cnt[128] by wave 0 via shuffles (no barriers inside)
    if (wid == 0) {
        int a  = cnt[lane];
        int b2v = cnt[lane + 64];
        int sa = a, sb = b2v;
        #pragma unroll
        for (int d = 1; d < 64; d <<= 1) {
            int na = __shfl_up(sa, d, 64);
            int nb = __shfl_up(sb, d, 64);
            if (lane >= d) { sa += na; sb += nb; }
        }
        int tot = __shfl(sa, 63, 64);
        sb += tot;
        cur[lane]      = sa - a;
        cur[lane + 64] = sb - b2v;
    }
    __syncthreads();                                        // #3

    // scatter (bijective: every entry gets a unique p in [0, NL))
    int p0 = atomicAdd(&cur[b0], 1);
    int p1 = atomicAdd(&cur[b1], 1);
    int p2 = atomicAdd(&cur[b2], 1);
    int p3 = atomicAdd(&cur[b3], 1);
    se[p0] = e0; pk[b * NL + p0] = make_float2(e0, __int_as_float(t));
    se[p1] = e1; pk[b * NL + p1] = make_float2(e1, __int_as_float(t + 256));
    se[p2] = e2; pk[b * NL + p2] = make_float2(e2, __int_as_float(t + 512));
    se[p3] = e3; pk[b * NL + p3] = make_float2(e3, __int_as_float(t + 768));
    __syncthreads();                                        // #4

    // per-chunk sums: wave w reduces chunks 4w..4w+3
    #pragma unroll
    for (int cc = 0; cc < 4; ++cc) {
        int chunk = wid * 4 + cc;
        float s = se[chunk * 64 + lane];
        #pragma unroll
        for (int off = 32; off > 0; off >>= 1)
            s += __shfl_xor(s, off, 64);
        if (lane == 0) csum[chunk] = s;
    }
    __syncthreads();                                        // #5

    // suffix masses at the 16 boundary slots attn actually reads
    if (t == 0) {
        float run = 0.0f;
        for (int c = 15; c >= 0; --c) {
            rem[b * NL + c * 64 + 63] = run;
            run += csum[c];
        }
    }
}

// ---------------- Kernel C: out[b,q,:] = sum_k p * value[b,k,:] ----------
// 512 threads = 8 waves; ONE WAVE = 4 ROWS of one batch; block = 32 rows.
// Top-64 V rows staged once per block in LDS (64KB, 2 blocks/CU). Walk =
// fixed 64 iterations: one ds_read_b128 feeds 4 accumulators; weights are
// scalar-selected (ballot u64 in SGPR, s_cselect of readlane'd e). Mask
// resolved by 4 per-lane gathers issued at kernel top (latency hides under
// staging + barrier). No compaction, no bpermute, no prefetch registers.
__global__ __launch_bounds__(512)
void attn_kernel(const float* __restrict__ value, const int* __restrict__ mask,
                 const float2* __restrict__ pk, const float* __restrict__ rem,
                 float* __restrict__ out) {
    __shared__ float lds_V[64 * ND];          // 64 KB: top-64 value rows

    const int wid  = threadIdx.x >> 6;        // 0..7
    const int lane = threadIdx.x & 63;
    const int row0 = blockIdx.x * 32 + wid * 4;   // wave's 4 rows
    const int b    = row0 >> 10;
    const int base = b << 10;

    const float4* vbase = (const float4*)(value + ((size_t)b << 10) * ND);
    const float2* pk_g  = pk + base;

    // top-64 metadata, lane-parallel (shared by all rows of the batch)
    float2 p0 = pk_g[lane];
    float e0  = p0.x;
    int   k0  = __float_as_int(p0.y);
    int   e0i = __float_as_int(e0);

    // 4 independent mask gathers, issued before staging (latency overlap)
    int mv0 = mask[(size_t)(row0 + 0) * NL + k0];
    int mv1 = mask[(size_t)(row0 + 1) * NL + k0];
    int mv2 = mask[(size_t)(row0 + 2) * NL + k0];
    int mv3 = mask[(size_t)(row0 + 3) * NL + k0];

    // stage top-64 V rows: wave w stages slots 8w..8w+7 (coalesced 1KB each)
    #pragma unroll
    for (int j = 0; j < 8; ++j) {
        int s   = wid * 8 + j;
        int ksr = __builtin_amdgcn_readlane(k0, s);    // uniform -> SGPR base
        ((float4*)lds_V)[s * 64 + lane] = vbase[(size_t)ksr * 64 + lane];
    }

    unsigned long long bm0 = __ballot(mv0 != 0);
    unsigned long long bm1 = __ballot(mv1 != 0);
    unsigned long long bm2 = __ballot(mv2 != 0);
    unsigned long long bm3 = __ballot(mv3 != 0);

    // Z per row: butterfly of mask-selected e (uniform result)
    auto zsum = [&](unsigned long long bm) -> float {
        float wz = ((bm >> lane) & 1ull) ? e0 : 0.0f;
        #pragma unroll
        for (int off = 32; off > 0; off >>= 1)
            wz += __shfl_xor(wz, off, 64);
        return wz;
    };
    float z0 = zsum(bm0), z1 = zsum(bm1), z2 = zsum(bm2), z3 = zsum(bm3);

    __syncthreads();   // lds_V ready

    // ---- walk: fixed 64 iterations over LDS; weights scalar-selected ----
    float4 acc0 = make_float4(0.f, 0.f, 0.f, 0.f);
    float4 acc1 = make_float4(0.f, 0.f, 0.f, 0.f);
    float4 acc2 = make_float4(0.f, 0.f, 0.f, 0.f);
    float4 acc3 = make_float4(0.f, 0.f, 0.f, 0.f);

    #pragma unroll 16
    for (int i = 0; i < 64; ++i) {
        float4 v = ((const float4*)lds_V)[i * 64 + lane];
        float ei = __int_as_float(__builtin_amdgcn_readlane(e0i, i));
        float w0 = ((bm0 >> i) & 1ull) ? ei : 0.0f;      // s_cselect
        float w1 = ((bm1 >> i) & 1ull) ? ei : 0.0f;
        float w2 = ((bm2 >> i) & 1ull) ? ei : 0.0f;
        float w3 = ((bm3 >> i) & 1ull) ? ei : 0.0f;
        acc0.x += w0 * v.x; acc0.y += w0 * v.y; acc0.z += w0 * v.z; acc0.w += w0 * v.w;
        acc1.x += w1 * v.x; acc1.y += w1 * v.y; acc1.z += w1 * v.z; acc1.w += w1 * v.w;
        acc2.x += w2 * v.x; acc2.y += w2 * v.y; acc2.z += w2 * v.z; acc2.w += w2 * v.w;
        acc3.x += w3 * v.x; acc3.y += w3 * v.y; acc3.z += w3 * v.z; acc3.w += w3 * v.w;
    }

    // ---- per-row epilogue: done check, rare deep chunks, store ----
    const float remv = rem[base + 63];

    auto finish_row = [&](int r, float4 acc, float Z) {
        const int* mrow = mask + (size_t)(row0 + r) * NL;
        bool done = (remv <= 1e-5f * Z);     // Z==0 -> rem>0 -> continue
        for (int c = 1; c < 16 && !done; ++c) {           // ~never taken
            float2 p = pk_g[c * 64 + lane];
            float e  = p.x;
            int   k  = __float_as_int(p.y);
            bool mb  = (mrow[k] != 0);
            float dz = mb ? e : 0.0f;
            #pragma unroll
            for (int off = 32; off > 0; off >>= 1)
                dz += __shfl_xor(dz, off, 64);
            unsigned long long bmx = __ballot(mb);
            int eI = __float_as_int(e);
            for (int i = 0; i < 64; ++i) {                // rolled: rare path
                float ei = __int_as_float(__builtin_amdgcn_readlane(eI, i));
                int   ki = __builtin_amdgcn_readlane(k, i);
                float w  = ((bmx >> i) & 1ull) ? ei : 0.0f;
                float4 v = vbase[(size_t)ki * 64 + lane];
                acc.x += w * v.x; acc.y += w * v.y;
                acc.z += w * v.z; acc.w += w * v.w;
            }
            Z += dz;
            done = (rem[base + c * 64 + 63] <= 1e-5f * Z);
        }
        float4* orow = (float4*)(out + (size_t)(row0 + r) * ND);
        if (Z > 0.0f) {
            float inv = 1.0f / Z;
            orow[lane] = make_float4(acc.x * inv, acc.y * inv,
                                     acc.z * inv, acc.w * inv);
        } else {
            // all-masked row: softmax over constant -1e9 -> uniform average
            float4 s = make_float4(0.f, 0.f, 0.f, 0.f);
            for (int k = 0; k < NL; ++k) {
                float4 v = vbase[(size_t)k * 64 + lane];
                s.x += v.x; s.y += v.y; s.z += v.z; s.w += v.w;
            }
            const float inv = 1.0f / (float)NL;
            orow[lane] = make_float4(s.x * inv, s.y * inv, s.z * inv, s.w * inv);
        }
    };
    finish_row(0, acc0, z0);
    finish_row(1, acc1, z1);
    finish_row(2, acc2, z2);
    finish_row(3, acc3, z3);
}

extern "C" void kernel_launch(void* const* d_in, const int* in_sizes, int n_in,
                              void* d_out, int out_size, void* d_ws, size_t ws_size,
                              hipStream_t stream) {
    // setup_inputs order: query, key, value, w, mask   (query unused!)
    const float* key   = (const float*)d_in[1];
    const float* value = (const float*)d_in[2];
    const float* w     = (const float*)d_in[3];
    const int*   mask  = (const int*)d_in[4];
    float*       outp  = (float*)d_out;

    float*  ks  = (float*)d_ws;                  // 16*1024 f32
    float2* pkb = (float2*)(ks + NB * NL);       // 16*1024 f32x2 (e, idx) bucket-desc
    float*  rem = (float*)(pkb + NB * NL);       // 16*1024 f32 suffix masses

    ks_kernel    <<<NB * NL / 4, 256, 0, stream>>>(key, w, ks);
    select_kernel<<<NB, 256, 0, stream>>>(ks, pkb, rem);
    attn_kernel  <<<NB * NL / 32, 512, 0, stream>>>(value, mask, pkb, rem, outp);
}